// Round 4
// baseline (241.769 us; speedup 1.0000x reference)
//
#include <hip/hip_runtime.h>

// DAGConstraintLayer: out[b,i] = sigmoid(min over root-to-i chain of x[b,i]).
// R6 (barrier-free persistent-wave pipeline) FAILED correctness with absmax
// 4.48 ~= max|x|: raw input reached out. Only possible if stage-out's
// ds_read_b128s (via reinterpret_cast<float4*>, dynamic idx) were hoisted
// above process_group's scalar float ds_writes — nothing fenced that boundary
// (R4 was protected by __syncthreads). R7 = R6 + compiler memory fences
// (asm ""::: "memory" + sched_barrier(0)) at EVERY phase boundary, and a
// uniform counted wait `s_waitcnt vmcnt(2)`:
//   top-of-iter FIFO = [loads(j):2, stores(j-1):2, loads(j+1):2]
//   vmcnt(2) drains loads(j) (+aged stores), always leaves prefetch in flight.
// Design recap: each WAVE owns 4 rows/step (508 floats = exactly 127 float4,
// wave-private, 16B-aligned), a private 2x2032B LDS double buffer, streams 8
// groups, prefetching g+2 via global_load_lds while computing g. 16
// threads/row, depth-4 register subtrees; all LDS deps same-wave program
// order. Zero __syncthreads. 16,256 B LDS -> 8 blocks/CU -> 32 waves/CU;
// grid = 2048 blocks (8 blocks/CU exactly).

#define NODES 127
#define RPG   4                      // rows per group (one wave step)
#define GF    (RPG * NODES)          // 508 floats per group
#define GF4   (GF / 4)               // 127 float4 per group
#define BLOCK 256
#define WPB   (BLOCK / 64)           // 4 waves per block
#define TILES 8                      // groups per wave

// Compiler-level memory fence (zero instructions) + machine-sched fence.
// Prevents IR passes AND the machine scheduler from moving LDS/VMEM ops
// across phase boundaries (the R6 bug: stage-out ds_reads hoisted above
// compute ds_writes through the float4/float type-pun).
#define FENCE() do { asm volatile("" ::: "memory");                 \
                     __builtin_amdgcn_sched_barrier(0); } while (0)

__device__ __forceinline__ float sigf(float v) {
    return 1.0f / (1.0f + __expf(-v));
}

// Stage one 508-float group into this wave's LDS slice. DMA dest is
// wave-uniform base + lane*16 (hardware-defined); source is per-lane.
// Lane 63 masked on the 2nd op (slot 127 doesn't exist: 64 + 63 = 127 f4).
__device__ __forceinline__ void stage_group(const float* __restrict__ x,
                                            long long g, float* b, int l) {
    const float4* src = (const float4*)x + g * GF4;
    __builtin_amdgcn_global_load_lds(
        (const __attribute__((address_space(1))) unsigned int*)(src + l),
        (__attribute__((address_space(3))) unsigned int*)b, 16, 0, 0);
    if (l < GF4 - 64) {              // lanes 0..62 cover f4 64..126
        __builtin_amdgcn_global_load_lds(
            (const __attribute__((address_space(1))) unsigned int*)(src + 64 + l),
            (__attribute__((address_space(3))) unsigned int*)(b + 256), 16, 0, 0);
    }
}

// Compute 4 rows in-place: 16 threads/row, one depth-4 subtree (7 nodes) each,
// plus nodes 7..14 via even-s and nodes 0..6 via s==0. ALL LDS reads precede
// ALL LDS writes; each row lives entirely in one wave, and a wave's DS ops
// execute in program order -> in-place update is safe without sync.
__device__ __forceinline__ void process_group(float* buf, int l) {
    const int rl = l >> 4;                       // row 0..3
    const int s  = l & 15;                       // 16 threads per row
    const int o  = rl * NODES;
    const int m1 = 1 + (s >> 3);                 // depth-1 ancestor
    const int m2 = 3 + (s >> 2);                 // depth-2 ancestor
    const int m3 = 7 + (s >> 1);                 // depth-3 ancestor
    const int m4 = 15 + s;                       // my depth-4 subtree root
    const int c0 = 2 * m4 + 1;                   // children: c0, c0+1
    const int g0 = 2 * c0 + 1;                   // leaves: g0..g0+3 (contiguous)

    // ---- reads ----
    const float x0 = buf[o];
    const float a1 = buf[o + m1];
    const float a2 = buf[o + m2];
    const float n3 = buf[o + m3];
    const float n4 = buf[o + m4];
    const float cA = buf[o + c0],     cB = buf[o + c0 + 1];
    const float gA = buf[o + g0],     gB = buf[o + g0 + 1];
    const float gC = buf[o + g0 + 2], gD = buf[o + g0 + 3];

    float X2 = 0.f, X4 = 0.f, X5 = 0.f, X6 = 0.f;
    if (s == 0) {                                // reads only, still before writes
        X2 = buf[o + 2]; X4 = buf[o + 4]; X5 = buf[o + 5]; X6 = buf[o + 6];
    }

    // ---- path-mins in registers ----
    const float pm  = fminf(fminf(x0, a1), a2);  // path to m3 (excl. m3) -> v_min3
    const float p3  = fminf(pm, n3);
    const float p4  = fminf(p3, n4);
    const float pc0 = fminf(p4, cA),  pc1 = fminf(p4, cB);
    const float pg0 = fminf(pc0, gA), pg1 = fminf(pc0, gB);
    const float pg2 = fminf(pc1, gC), pg3 = fminf(pc1, gD);

    // ---- writes ----
    if (s == 0) {                                // nodes 0..6; here m1==1, m2==3
        const float p1 = fminf(x0, a1);
        const float p2 = fminf(x0, X2);
        buf[o + 0] = sigf(x0);
        buf[o + 1] = sigf(p1);
        buf[o + 2] = sigf(p2);
        buf[o + 3] = sigf(fminf(p1, a2));
        buf[o + 4] = sigf(fminf(p1, X4));
        buf[o + 5] = sigf(fminf(p2, X5));
        buf[o + 6] = sigf(fminf(p2, X6));
    }
    if ((s & 1) == 0) buf[o + m3] = sigf(p3);    // nodes 7..14, written once
    buf[o + m4]     = sigf(p4);
    buf[o + c0]     = sigf(pc0); buf[o + c0 + 1] = sigf(pc1);
    buf[o + g0]     = sigf(pg0); buf[o + g0 + 1] = sigf(pg1);
    buf[o + g0 + 2] = sigf(pg2); buf[o + g0 + 3] = sigf(pg3);
}

__global__ __launch_bounds__(BLOCK, 8) void dag_kernel(const float* __restrict__ x,
                                                       float* __restrict__ out) {
    __shared__ float lds[WPB * 2 * GF];          // 4 waves * 2 bufs * 2032 B = 16,256 B

    const int t  = threadIdx.x;
    const int wv = t >> 6;
    const int l  = t & 63;
    const long long W = (long long)blockIdx.x * WPB + wv;   // global wave id
    const long long gbase = W * TILES;

    float* const b0 = lds + (wv * 2 + 0) * GF;   // wave-private double buffer
    float* const b1 = lds + (wv * 2 + 1) * GF;

    // prologue: fill both buffers (2 VMEM ops each); FENCE pins FIFO order
    // (g0's loads strictly older than g1's).
    stage_group(x, gbase + 0, b0, l);
    FENCE();
    stage_group(x, gbase + 1, b1, l);

    #pragma unroll
    for (int j = 0; j < TILES; ++j) {
        float* buf = (j & 1) ? b1 : b0;

        // Drain own loads(j); keep loads(j+1) in flight (never vmcnt(0)).
        FENCE();
        asm volatile("s_waitcnt vmcnt(2)" ::: "memory");
        __builtin_amdgcn_sched_barrier(0);

        process_group(buf, l);

        // Order compute ds_writes BEFORE stage-out ds_reads (the R6 bug).
        FENCE();

        // stage-out: own-wave LDS only; the dependent global stores force the
        // compiler's lgkmcnt wait after the ds_read_b128s.
        {
            const float4* b4 = (const float4*)buf;
            float4* dst = (float4*)out + (gbase + j) * GF4;
            dst[l] = b4[l];
            if (l < GF4 - 64) dst[64 + l] = b4[64 + l];
        }

        // Prefetch group j+2 into the buffer just consumed. Safe: the stores
        // above already drained this buffer's ds_reads (store data dep), and
        // the FENCE pins the DMA issue after them.
        FENCE();
        if (j + 2 < TILES) stage_group(x, gbase + j + 2, buf, l);
    }
}

extern "C" void kernel_launch(void* const* d_in, const int* in_sizes, int n_in,
                              void* d_out, int out_size, void* d_ws, size_t ws_size,
                              hipStream_t stream) {
    const float* x = (const float*)d_in[0];
    float* out = (float*)d_out;
    int rows        = in_sizes[0] / NODES;       // 262144
    int groups      = rows / RPG;                // 65536
    int total_waves = groups / TILES;            // 8192
    int grid        = total_waves / WPB;         // 2048 = 8 blocks/CU exactly
    dag_kernel<<<grid, BLOCK, 0, stream>>>(x, out);
}

// Round 5
// 238.900 us; speedup vs baseline: 1.0120x; 1.0120x over previous
//
#include <hip/hip_runtime.h>

// DAGConstraintLayer: out[b,i] = sigmoid(min over root-to-i chain of x[b,i]).
// R7 post-mortem: zero-barrier persistent-wave LDS pipeline (88us) did NOT
// beat the simple barrier version (83us). Three unrelated schedules all sit
// at ~2.4 TB/s with every pipe <35% -> the schedule is not the variable.
// Common to all: the LDS-staging skeleton (every byte through the LDS pipe
// twice + DMA). R8 eliminates LDS entirely: one WAVE = one ROW (127 floats);
// lane l holds node l (slot A) and node 64+l (slot B, lanes 0..62 - all
// depth-6 leaves). Ancestor path-min via pointer-doubling ds_bpermute jumps
// 1,2,4 (anc_k(l) = ((l+1)>>k)-1, negatives clamped to 0 = root, always
// sound): after 1+2+4 each lane's min covers an 8-chain >= deepest need
// (node 63, chain 7). Slot B needs one more bpermute from its (final) parent
// lane (63+l)>>1. sigmoid(min(x-chain)) == min(sigmoid-chain) since sigmoid
// is monotone. Loads/stores are plain coalesced dword register streams;
// 4-slot register rotation with prefetch distance 2 bounds in-flight loads
// (WAR on the slot regs) - compiler emits counted per-register waitcnts.
// No LDS, no barriers, no inline-asm waits. This is also the control
// experiment: as close to pure streaming as a correct kernel gets. If this
// TOO lands at ~83us, ~2.4 TB/s is this workload's memory-system ceiling
// (4-design evidence) -> roofline.

#define NODES 127
#define BLOCK 256
#define WPB   (BLOCK / 64)           // 4 waves per block
#define TPW   32                     // rows per wave

__device__ __forceinline__ float sigf(float v) {
    return 1.0f / (1.0f + __expf(-v));
}

__device__ __forceinline__ float bperm_min(float p, int idx) {
    return fminf(p, __int_as_float(
        __builtin_amdgcn_ds_bpermute(idx, __float_as_int(p))));
}

__global__ __launch_bounds__(BLOCK, 8) void dag_kernel(const float* __restrict__ x,
                                                       float* __restrict__ out) {
    const int t  = threadIdx.x;
    const int wv = t >> 6;
    const int l  = t & 63;
    const long long W    = (long long)blockIdx.x * WPB + wv;  // global wave id
    const long long row0 = W * TPW;                           // first row

    // Loop-invariant per-lane bpermute byte-indices (pointer-doubling jumps).
    const int i1 = ((l + 1) >> 1) - 1;
    const int i2 = ((l + 1) >> 2) - 1;
    const int i4 = ((l + 1) >> 4) - 1;
    const int s1 = 4 * (i1 < 0 ? 0 : i1);
    const int s2 = 4 * (i2 < 0 ? 0 : i2);
    const int s4 = 4 * (i4 < 0 ? 0 : i4);
    const int sB = 4 * ((63 + l) >> 1);   // parent lane of node 64+l (depth-5)
    const int lb = (l < 63) ? l : 62;     // clamp lane-63 slot-B load (dummy;
                                          // avoids 4B OOB read on final row)

    const float* __restrict__ xp = x   + row0 * NODES;
    float*       __restrict__ op = out + row0 * NODES;

    float A[4], B[4];                     // rotation slots (static idx only)

#define LOADROW(j, slot) do {                                   \
        const float* rp_ = xp + (size_t)(j) * NODES;            \
        A[slot] = rp_[l];                                       \
        B[slot] = rp_[64 + lb];                                 \
    } while (0)

    LOADROW(0, 0);
    LOADROW(1, 1);

    #pragma unroll
    for (int j = 0; j < TPW; ++j) {
        const int cs = j & 3;
        if (j + 2 < TPW) LOADROW(j + 2, (j + 2) & 3);   // prefetch distance 2

        // ---- slot A: min over ancestor chain via jumps 1,2,4 ----
        float p = A[cs];
        p = bperm_min(p, s1);
        p = bperm_min(p, s2);
        p = bperm_min(p, s4);
        // ---- slot B: depth-6 leaves; parent path-min is already final ----
        float q = fminf(B[cs], __int_as_float(
            __builtin_amdgcn_ds_bpermute(sB, __float_as_int(p))));

        float* rp = op + (size_t)j * NODES;
        rp[l] = sigf(p);                  // nodes 0..63, all 64 lanes
        if (l < 63) rp[64 + l] = sigf(q); // nodes 64..126
    }
#undef LOADROW
}

extern "C" void kernel_launch(void* const* d_in, const int* in_sizes, int n_in,
                              void* d_out, int out_size, void* d_ws, size_t ws_size,
                              hipStream_t stream) {
    const float* x = (const float*)d_in[0];
    float* out = (float*)d_out;
    int rows  = in_sizes[0] / NODES;      // 262144
    int waves = rows / TPW;               // 8192
    int grid  = waves / WPB;              // 2048 = 8 blocks/CU exactly
    dag_kernel<<<grid, BLOCK, 0, stream>>>(x, out);
}